// Round 2
// baseline (825.765 us; speedup 1.0000x reference)
//
#include <hip/hip_runtime.h>

typedef __attribute__((ext_vector_type(8))) short short8;
typedef __attribute__((ext_vector_type(4))) float float4_;

#define SDIM    137
#define HID     256
#define K0PAD   160     // state (137) padded to 5 k-blocks of 32
#define KAUG    416     // 256 (h) + 160 (state part)
#define MTILE   64

__device__ __forceinline__ unsigned short f2bf(float f) {
  union { float f; unsigned int i; } v; v.f = f;
  unsigned int u = v.i;
  u = u + 0x7FFFu + ((u >> 16) & 1u);   // RNE
  return (unsigned short)(u >> 16);
}
__device__ __forceinline__ float bf2f(unsigned short u) {
  union { unsigned int i; float f; } v; v.i = ((unsigned int)u) << 16; return v.f;
}
__device__ __forceinline__ float fast_tanh(float x) {
  x = fminf(fmaxf(x, -15.f), 15.f);
  float e = __expf(2.f * x);
  return (e - 1.f) / (e + 1.f);
}
// XOR chunk swizzle: 16B chunks, spreads rows across bank groups, zero padding.
__device__ __forceinline__ int swz(int row, int col) {
  return row * 256 + ((((col >> 3) ^ (row & 7)) << 3) | (col & 7));
}

// One GEMM pass: acc[4][4] (+=) A(LDS bf16, 64xK swizzled) @ B(global bf16, [N][K] row-major)^T
// Verified fragment layouts (m89/m91/m120):
//   A: lane reads row (lane&15), k = kb*32 + (lane>>4)*8 .. +7  (one 16B chunk)
//   B: lane reads W row n = colbase+(lane&15), same k window (row-major W == B^T)
template<int NK, int LDB, int BOFF>
__device__ __forceinline__ void mma_step(const unsigned short* A,
                                         const unsigned short* B,
                                         float4_ (&acc)[4][4], int lane, int wave)
{
  const int rq = lane >> 4;
  const int rm = lane & 15;
  #pragma unroll
  for (int kb = 0; kb < NK; ++kb) {
    short8 af[4]; short8 bfr[4];
    #pragma unroll
    for (int r = 0; r < 4; ++r) {
      int m = r * 16 + rm;
      int chunk = kb * 4 + rq;
      af[r] = *(const short8*)(A + m * 256 + ((chunk ^ (m & 7)) << 3));
    }
    #pragma unroll
    for (int c = 0; c < 4; ++c) {
      int n = wave * 64 + c * 16 + rm;
      bfr[c] = *(const short8*)(B + n * LDB + BOFF + kb * 32 + rq * 8);
    }
    #pragma unroll
    for (int r = 0; r < 4; ++r)
      #pragma unroll
      for (int c = 0; c < 4; ++c)
        acc[r][c] = __builtin_amdgcn_mfma_f32_16x16x32_bf16(af[r], bfr[c], acc[r][c], 0, 0, 0);
  }
}

// ---------------- prep kernels (tiny, once per launch) ----------------
// All raw inputs are FP32 (per reference). Prep converts weights to bf16.

// W0p[256][160] bf16: W0 state columns, zero-padded; sin/cos(t) cols folded into b0p (fp32).
__global__ void prep_w0(const float* __restrict__ t,
                        const float* __restrict__ W0,
                        const float* __restrict__ b0,
                        unsigned short* __restrict__ W0p,
                        float* __restrict__ b0p)
{
  int n = threadIdx.x;               // 256 threads
  float tv  = t[0];
  float ang = tv * (6.2831853071795864f / 24.0f);
  float sv = __sinf(ang), cv = __cosf(ang);
  for (int k = 0; k < K0PAD; ++k)
    W0p[n * K0PAD + k] = (k < SDIM) ? f2bf(W0[n * 139 + k]) : (unsigned short)0;
  b0p[n] = b0[n] + W0[n * 139 + 137] * sv + W0[n * 139 + 138] * cv;
}

// Waug[256][416] bf16: k<256 -> Wout (rows>=137 zero); k=256+s -> 0.1*(M - I) for the
// two collapsed seq-len-1 attentions (M = out_w @ Wv).
// baug (fp32) folds bout + 0.1*(out_w@bv + out_b).
__global__ void prep_waug(const float* __restrict__ Wout,
                          const float* __restrict__ bout,
                          const float* __restrict__ lm_in_w,
                          const float* __restrict__ lm_in_b,
                          const float* __restrict__ lm_out_w,
                          const float* __restrict__ lm_out_b,
                          const float* __restrict__ ta_in_w,
                          const float* __restrict__ ta_in_b,
                          const float* __restrict__ ta_out_w,
                          const float* __restrict__ ta_out_b,
                          unsigned short* __restrict__ Waug,
                          float* __restrict__ baug)
{
  int n = blockIdx.x;                // 256 blocks
  int t = threadIdx.x;               // 64 threads
  for (int k = t; k < KAUG; k += 64) {
    float v = 0.f;
    if (k < 256) {
      if (n < SDIM) v = Wout[n * 256 + k];
    } else {
      int s = k - 256;
      if (s < 136) {
        if (n < 128 && s < 128) {
          // Mta[n][s] = sum_r ta_out_w[n][r] * ta_Wv[r][s], ta_Wv = ta_in_w rows 256..383
          float dot = 0.f;
          for (int r = 0; r < 128; ++r)
            dot += ta_out_w[n * 128 + r] * ta_in_w[(256 + r) * 128 + s];
          v = 0.1f * (dot - (s == n ? 1.f : 0.f));
        } else if (n >= 128 && n < 136 && s >= 128) {
          int a = n - 128, b = s - 128;
          float dot = 0.f;
          for (int r = 0; r < 8; ++r)
            dot += lm_out_w[a * 8 + r] * lm_in_w[(16 + r) * 8 + b];
          v = 0.1f * (dot - (s == n ? 1.f : 0.f));
        }
      }
    }
    Waug[n * KAUG + k] = f2bf(v);
  }
  if (t == 0) {
    float bb = 0.f;
    if (n < SDIM) bb = bout[n];
    if (n < 128) {
      float dot = 0.f;
      for (int r = 0; r < 128; ++r)
        dot += ta_out_w[n * 128 + r] * ta_in_b[256 + r];
      bb += 0.1f * (dot + ta_out_b[n]);
    } else if (n < 136) {
      int a = n - 128;
      float dot = 0.f;
      for (int r = 0; r < 8; ++r)
        dot += lm_out_w[a * 8 + r] * lm_in_b[16 + r];
      bb += 0.1f * (dot + lm_out_b[a]);
    }
    baug[n] = bb;
  }
}

// bf16 copies of the residual-block weights (read every block, keep them 2B/elem).
__global__ void prep_blk(const float* __restrict__ src, unsigned short* __restrict__ dst, int n) {
  int i = blockIdx.x * 256 + threadIdx.x;
  if (i < n) dst[i] = f2bf(src[i]);
}

// ---------------- fused main kernel ----------------

__global__ __launch_bounds__(256, 2) void fused_odefunc(
    const float* __restrict__ state,
    const unsigned short* __restrict__ W0p,
    const float* __restrict__ b0p,
    const unsigned short* __restrict__ blkW1,
    const float* __restrict__ blkb1,
    const unsigned short* __restrict__ blkW2,
    const float* __restrict__ blkb2,
    const unsigned short* __restrict__ Waug,
    const float* __restrict__ baug,
    float* __restrict__ out)
{
  __shared__ unsigned short P[64 * 256];   // ping
  __shared__ unsigned short Q[64 * 256];   // pong  (total = exactly 64 KiB)
  const int tid  = threadIdx.x;
  const int lane = tid & 63;
  const int wave = tid >> 6;
  const int rq   = lane >> 4;
  const int rm   = lane & 15;
  const int row0 = blockIdx.x * MTILE;

  // stage state tile (fp32 -> bf16) -> P  (cols [137,160) zero)
  for (int idx = tid; idx < MTILE * K0PAD; idx += 256) {
    int m = idx / K0PAD;
    int k = idx - m * K0PAD;
    unsigned short v = 0;
    if (k < SDIM) v = f2bf(state[(size_t)(row0 + m) * SDIM + k]);
    P[swz(m, k)] = v;
  }
  __syncthreads();

  // ---- layer 0: h = relu(x @ W0p^T + b0p) -> Q
  {
    float4_ acc[4][4];
    #pragma unroll
    for (int r = 0; r < 4; ++r)
      #pragma unroll
      for (int c = 0; c < 4; ++c) acc[r][c] = (float4_){0.f, 0.f, 0.f, 0.f};
    mma_step<K0PAD / 32, K0PAD, 0>(P, W0p, acc, lane, wave);
    #pragma unroll
    for (int c = 0; c < 4; ++c) {
      int col = wave * 64 + c * 16 + rm;
      float bb = b0p[col];
      #pragma unroll
      for (int r = 0; r < 4; ++r)
        #pragma unroll
        for (int i = 0; i < 4; ++i) {
          int row = r * 16 + rq * 4 + i;
          Q[swz(row, col)] = f2bf(fmaxf(acc[r][c][i] + bb, 0.f));
        }
    }
  }
  __syncthreads();

  // ---- 4 residual blocks: g = tanh(h@W1^T+b1); h = tanh(h + g@W2^T+b2)
  for (int blk = 0; blk < 4; ++blk) {
    const unsigned short* W1 = blkW1 + (size_t)blk * 65536;
    const float*          b1 = blkb1 + blk * 256;
    const unsigned short* W2 = blkW2 + (size_t)blk * 65536;
    const float*          b2 = blkb2 + blk * 256;

    float4_ acc[4][4];
    #pragma unroll
    for (int r = 0; r < 4; ++r)
      #pragma unroll
      for (int c = 0; c < 4; ++c) acc[r][c] = (float4_){0.f, 0.f, 0.f, 0.f};
    mma_step<8, 256, 0>(Q, W1, acc, lane, wave);
    // write g -> P (P's last readers finished before the previous barrier)
    #pragma unroll
    for (int c = 0; c < 4; ++c) {
      int col = wave * 64 + c * 16 + rm;
      float bb = b1[col];
      #pragma unroll
      for (int r = 0; r < 4; ++r)
        #pragma unroll
        for (int i = 0; i < 4; ++i) {
          int row = r * 16 + rq * 4 + i;
          P[swz(row, col)] = f2bf(fast_tanh(acc[r][c][i] + bb));
        }
    }
    __syncthreads();

    #pragma unroll
    for (int r = 0; r < 4; ++r)
      #pragma unroll
      for (int c = 0; c < 4; ++c) acc[r][c] = (float4_){0.f, 0.f, 0.f, 0.f};
    mma_step<8, 256, 0>(P, W2, acc, lane, wave);
    // h_new = tanh(h_old + inner + b2), in-place on Q (each lane owns its slots)
    #pragma unroll
    for (int c = 0; c < 4; ++c) {
      int col = wave * 64 + c * 16 + rm;
      float bb = b2[col];
      #pragma unroll
      for (int r = 0; r < 4; ++r)
        #pragma unroll
        for (int i = 0; i < 4; ++i) {
          int row = r * 16 + rq * 4 + i;
          float hn = fast_tanh(bf2f(Q[swz(row, col)]) + acc[r][c][i] + bb);
          Q[swz(row, col)] = f2bf(hn);
        }
    }
    __syncthreads();
  }

  // ---- final: out = [h, state] @ Waug^T + baug  (core + 0.1*delta folded)
  // restage state -> P (P free since last barrier; nobody reads it until after next barrier)
  for (int idx = tid; idx < MTILE * K0PAD; idx += 256) {
    int m = idx / K0PAD;
    int k = idx - m * K0PAD;
    unsigned short v = 0;
    if (k < SDIM) v = f2bf(state[(size_t)(row0 + m) * SDIM + k]);
    P[swz(m, k)] = v;
  }
  {
    float4_ acc[4][4];
    #pragma unroll
    for (int r = 0; r < 4; ++r)
      #pragma unroll
      for (int c = 0; c < 4; ++c) acc[r][c] = (float4_){0.f, 0.f, 0.f, 0.f};
    mma_step<8, KAUG, 0>(Q, Waug, acc, lane, wave);        // h part (k 0..255)
    __syncthreads();                                        // staging visible
    mma_step<5, KAUG, 256>(P, Waug, acc, lane, wave);       // state part (k 256..415)
    #pragma unroll
    for (int c = 0; c < 4; ++c) {
      int col = wave * 64 + c * 16 + rm;
      if (col < SDIM) {
        float bb = baug[col];
        #pragma unroll
        for (int r = 0; r < 4; ++r)
          #pragma unroll
          for (int i = 0; i < 4; ++i) {
            int row = r * 16 + rq * 4 + i;
            out[(size_t)(row0 + row) * SDIM + col] = acc[r][c][i] + bb;
          }
      }
    }
  }
}

extern "C" void kernel_launch(void* const* d_in, const int* in_sizes, int n_in,
                              void* d_out, int out_size, void* d_ws, size_t ws_size,
                              hipStream_t stream) {
  const float* t        = (const float*)d_in[0];
  const float* state    = (const float*)d_in[1];
  const float* W0       = (const float*)d_in[2];
  const float* b0       = (const float*)d_in[3];
  const float* blkW1    = (const float*)d_in[4];
  const float* blkb1    = (const float*)d_in[5];
  const float* blkW2    = (const float*)d_in[6];
  const float* blkb2    = (const float*)d_in[7];
  const float* Wout     = (const float*)d_in[8];
  const float* bout     = (const float*)d_in[9];
  const float* lm_in_w  = (const float*)d_in[10];
  const float* lm_in_b  = (const float*)d_in[11];
  const float* lm_out_w = (const float*)d_in[12];
  const float* lm_out_b = (const float*)d_in[13];
  const float* ta_in_w  = (const float*)d_in[14];
  const float* ta_in_b  = (const float*)d_in[15];
  const float* ta_out_w = (const float*)d_in[16];
  const float* ta_out_b = (const float*)d_in[17];

  char* ws = (char*)d_ws;
  unsigned short* W0p   = (unsigned short*)ws;                   // 256*160*2   = 81920
  float*          b0p   = (float*)(ws + 81920);                  // 1024
  unsigned short* Waug  = (unsigned short*)(ws + 82944);         // 256*416*2   = 212992
  float*          baug  = (float*)(ws + 295936);                 // 1024
  unsigned short* W1b   = (unsigned short*)(ws + 296960);        // 4*256*256*2 = 524288
  unsigned short* W2b   = (unsigned short*)(ws + 821248);        // 524288  (total ~1.31 MB)

  prep_w0<<<1, 256, 0, stream>>>(t, W0, b0, W0p, b0p);
  prep_waug<<<256, 64, 0, stream>>>(Wout, bout, lm_in_w, lm_in_b, lm_out_w, lm_out_b,
                                    ta_in_w, ta_in_b, ta_out_w, ta_out_b, Waug, baug);
  prep_blk<<<(262144 + 255) / 256, 256, 0, stream>>>(blkW1, W1b, 262144);
  prep_blk<<<(262144 + 255) / 256, 256, 0, stream>>>(blkW2, W2b, 262144);

  int batch = in_sizes[1] / SDIM;               // 131072
  fused_odefunc<<<batch / MTILE, 256, 0, stream>>>(
      state, W0p, b0p, W1b, blkb1, W2b, blkb2, Waug, baug,
      (float*)d_out);
}

// Round 3
// 762.089 us; speedup vs baseline: 1.0836x; 1.0836x over previous
//
#include <hip/hip_runtime.h>

typedef __attribute__((ext_vector_type(8))) short short8;
typedef __attribute__((ext_vector_type(4))) float float4_;

#define SDIM    137
#define HID     256
#define K0PAD   160     // state (137) padded to 5 k-blocks of 32
#define KAUG    416     // 256 (h) + 160 (state part)
#define MTILE   64
#define NTHR    512     // 8 waves; each wave owns a 32-col strip

__device__ __forceinline__ unsigned short f2bf(float f) {
  union { float f; unsigned int i; } v; v.f = f;
  return (unsigned short)((v.i + 0x8000u) >> 16);   // round-half-up (2 ops)
}
__device__ __forceinline__ float bf2f(unsigned short u) {
  union { unsigned int i; float f; } v; v.i = ((unsigned int)u) << 16; return v.f;
}
__device__ __forceinline__ float fast_tanh(float x) {
  x = fminf(fmaxf(x, -15.f), 15.f);
  float e = __expf(2.f * x);
  return (e - 1.f) / (e + 1.f);
}
// XOR chunk swizzle: 16B chunks, spreads rows across bank groups, zero padding.
__device__ __forceinline__ int swz(int row, int col) {
  return row * 256 + ((((col >> 3) ^ (row & 7)) << 3) | (col & 7));
}

// acc[4][2] (+=) A(LDS bf16, 64xK swizzled) @ B(global bf16, [N][K] row-major)^T
// for this wave's 32-col strip (colbase = wave*32).
// Verified fragment layouts (m89/m91/m120):
//   A: lane reads row (lane&15)+16r, k = kb*32 + (lane>>4)*8 .. +7 (one 16B chunk)
//   B: lane reads W row n = colbase+c*16+(lane&15), same k window
template<int NK, int LDB, int BOFF>
__device__ __forceinline__ void mma_step(const unsigned short* A,
                                         const unsigned short* B,
                                         float4_ (&acc)[4][2], int lane, int colbase)
{
  const int rq = lane >> 4;
  const int rm = lane & 15;
  #pragma unroll
  for (int kb = 0; kb < NK; ++kb) {
    short8 af[4]; short8 bfr[2];
    #pragma unroll
    for (int r = 0; r < 4; ++r) {
      int m = r * 16 + rm;
      int chunk = kb * 4 + rq;
      af[r] = *(const short8*)(A + m * 256 + ((chunk ^ (m & 7)) << 3));
    }
    #pragma unroll
    for (int c = 0; c < 2; ++c) {
      int n = colbase + c * 16 + rm;
      bfr[c] = *(const short8*)(B + n * LDB + BOFF + kb * 32 + rq * 8);
    }
    #pragma unroll
    for (int r = 0; r < 4; ++r)
      #pragma unroll
      for (int c = 0; c < 2; ++c)
        acc[r][c] = __builtin_amdgcn_mfma_f32_16x16x32_bf16(af[r], bfr[c], acc[r][c], 0, 0, 0);
  }
}

// ---------------- prep kernels (tiny, once per launch) ----------------
// All raw inputs are FP32 (per reference). Prep converts weights to bf16.

__global__ void prep_w0(const float* __restrict__ t,
                        const float* __restrict__ W0,
                        const float* __restrict__ b0,
                        unsigned short* __restrict__ W0p,
                        float* __restrict__ b0p)
{
  int n = threadIdx.x;               // 256 threads
  float tv  = t[0];
  float ang = tv * (6.2831853071795864f / 24.0f);
  float sv = __sinf(ang), cv = __cosf(ang);
  for (int k = 0; k < K0PAD; ++k)
    W0p[n * K0PAD + k] = (k < SDIM) ? f2bf(W0[n * 139 + k]) : (unsigned short)0;
  b0p[n] = b0[n] + W0[n * 139 + 137] * sv + W0[n * 139 + 138] * cv;
}

// Waug[256][416] bf16: k<256 -> Wout (rows>=137 zero); k=256+s -> 0.1*(M - I) for the
// two collapsed seq-len-1 attentions (softmax over 1 key == 1, so MHA == out_w@Wv + consts).
// baug (fp32) folds bout + 0.1*(out_w@bv + out_b).
__global__ void prep_waug(const float* __restrict__ Wout,
                          const float* __restrict__ bout,
                          const float* __restrict__ lm_in_w,
                          const float* __restrict__ lm_in_b,
                          const float* __restrict__ lm_out_w,
                          const float* __restrict__ lm_out_b,
                          const float* __restrict__ ta_in_w,
                          const float* __restrict__ ta_in_b,
                          const float* __restrict__ ta_out_w,
                          const float* __restrict__ ta_out_b,
                          unsigned short* __restrict__ Waug,
                          float* __restrict__ baug)
{
  int n = blockIdx.x;                // 256 blocks
  int t = threadIdx.x;               // 64 threads
  for (int k = t; k < KAUG; k += 64) {
    float v = 0.f;
    if (k < 256) {
      if (n < SDIM) v = Wout[n * 256 + k];
    } else {
      int s = k - 256;
      if (s < 136) {
        if (n < 128 && s < 128) {
          float dot = 0.f;
          for (int r = 0; r < 128; ++r)
            dot += ta_out_w[n * 128 + r] * ta_in_w[(256 + r) * 128 + s];
          v = 0.1f * (dot - (s == n ? 1.f : 0.f));
        } else if (n >= 128 && n < 136 && s >= 128) {
          int a = n - 128, b = s - 128;
          float dot = 0.f;
          for (int r = 0; r < 8; ++r)
            dot += lm_out_w[a * 8 + r] * lm_in_w[(16 + r) * 8 + b];
          v = 0.1f * (dot - (s == n ? 1.f : 0.f));
        }
      }
    }
    Waug[n * KAUG + k] = f2bf(v);
  }
  if (t == 0) {
    float bb = 0.f;
    if (n < SDIM) bb = bout[n];
    if (n < 128) {
      float dot = 0.f;
      for (int r = 0; r < 128; ++r)
        dot += ta_out_w[n * 128 + r] * ta_in_b[256 + r];
      bb += 0.1f * (dot + ta_out_b[n]);
    } else if (n < 136) {
      int a = n - 128;
      float dot = 0.f;
      for (int r = 0; r < 8; ++r)
        dot += lm_out_w[a * 8 + r] * lm_in_b[16 + r];
      bb += 0.1f * (dot + lm_out_b[a]);
    }
    baug[n] = bb;
  }
}

// bf16 copies of the residual-block weights.
__global__ void prep_blk(const float* __restrict__ src, unsigned short* __restrict__ dst, int n) {
  int i = blockIdx.x * 256 + threadIdx.x;
  if (i < n) dst[i] = f2bf(src[i]);
}

// ---------------- fused main kernel ----------------
// 512 thr / 8 waves, 32-col strip per wave; 64KB LDS -> 2 blocks/CU = 16 waves/CU.

__global__ __launch_bounds__(NTHR, 4) void fused_odefunc(
    const float* __restrict__ state,
    const unsigned short* __restrict__ W0p,
    const float* __restrict__ b0p,
    const unsigned short* __restrict__ blkW1,
    const float* __restrict__ blkb1,
    const unsigned short* __restrict__ blkW2,
    const float* __restrict__ blkb2,
    const unsigned short* __restrict__ Waug,
    const float* __restrict__ baug,
    float* __restrict__ out)
{
  __shared__ unsigned short P[64 * 256];   // ping
  __shared__ unsigned short Q[64 * 256];   // pong  (total = exactly 64 KiB)
  const int tid  = threadIdx.x;
  const int lane = tid & 63;
  const int wave = tid >> 6;               // 0..7
  const int rq   = lane >> 4;
  const int rm   = lane & 15;
  const int cb   = wave * 32;              // this wave's column base
  const int row0 = blockIdx.x * MTILE;

  // stage state tile (fp32 -> bf16) -> P  (cols [137,160) zero)
  for (int idx = tid; idx < MTILE * K0PAD; idx += NTHR) {
    int m = idx / K0PAD;
    int k = idx - m * K0PAD;
    unsigned short v = 0;
    if (k < SDIM) v = f2bf(state[(size_t)(row0 + m) * SDIM + k]);
    P[swz(m, k)] = v;
  }
  __syncthreads();

  // ---- layer 0: h = relu(x @ W0p^T + b0p) -> Q
  {
    float4_ acc[4][2];
    #pragma unroll
    for (int r = 0; r < 4; ++r)
      #pragma unroll
      for (int c = 0; c < 2; ++c) acc[r][c] = (float4_){0.f, 0.f, 0.f, 0.f};
    mma_step<K0PAD / 32, K0PAD, 0>(P, W0p, acc, lane, cb);
    #pragma unroll
    for (int c = 0; c < 2; ++c) {
      int col = cb + c * 16 + rm;
      float bb = b0p[col];
      #pragma unroll
      for (int r = 0; r < 4; ++r)
        #pragma unroll
        for (int i = 0; i < 4; ++i) {
          int row = r * 16 + rq * 4 + i;
          Q[swz(row, col)] = f2bf(fmaxf(acc[r][c][i] + bb, 0.f));
        }
    }
  }
  __syncthreads();

  // ---- 4 residual blocks: g = tanh(h@W1^T+b1); h = tanh(h + g@W2^T+b2)
  for (int blk = 0; blk < 4; ++blk) {
    const unsigned short* W1 = blkW1 + (size_t)blk * 65536;
    const float*          b1 = blkb1 + blk * 256;
    const unsigned short* W2 = blkW2 + (size_t)blk * 65536;
    const float*          b2 = blkb2 + blk * 256;

    float4_ acc[4][2];
    #pragma unroll
    for (int r = 0; r < 4; ++r)
      #pragma unroll
      for (int c = 0; c < 2; ++c) acc[r][c] = (float4_){0.f, 0.f, 0.f, 0.f};
    mma_step<8, 256, 0>(Q, W1, acc, lane, cb);
    // write g -> P (P's last readers finished before the previous barrier)
    #pragma unroll
    for (int c = 0; c < 2; ++c) {
      int col = cb + c * 16 + rm;
      float bb = b1[col];
      #pragma unroll
      for (int r = 0; r < 4; ++r)
        #pragma unroll
        for (int i = 0; i < 4; ++i) {
          int row = r * 16 + rq * 4 + i;
          P[swz(row, col)] = f2bf(fast_tanh(acc[r][c][i] + bb));
        }
    }
    __syncthreads();

    #pragma unroll
    for (int r = 0; r < 4; ++r)
      #pragma unroll
      for (int c = 0; c < 2; ++c) acc[r][c] = (float4_){0.f, 0.f, 0.f, 0.f};
    mma_step<8, 256, 0>(P, W2, acc, lane, cb);
    // h_new = tanh(h_old + inner + b2), in-place on Q (each lane owns its slots)
    #pragma unroll
    for (int c = 0; c < 2; ++c) {
      int col = cb + c * 16 + rm;
      float bb = b2[col];
      #pragma unroll
      for (int r = 0; r < 4; ++r)
        #pragma unroll
        for (int i = 0; i < 4; ++i) {
          int row = r * 16 + rq * 4 + i;
          float hn = fast_tanh(bf2f(Q[swz(row, col)]) + acc[r][c][i] + bb);
          Q[swz(row, col)] = f2bf(hn);
        }
    }
    __syncthreads();
  }

  // ---- final: out = [h, state] @ Waug^T + baug  (core + 0.1*delta folded)
  // restage state -> P (P free since last barrier)
  for (int idx = tid; idx < MTILE * K0PAD; idx += NTHR) {
    int m = idx / K0PAD;
    int k = idx - m * K0PAD;
    unsigned short v = 0;
    if (k < SDIM) v = f2bf(state[(size_t)(row0 + m) * SDIM + k]);
    P[swz(m, k)] = v;
  }
  {
    float4_ acc[4][2];
    #pragma unroll
    for (int r = 0; r < 4; ++r)
      #pragma unroll
      for (int c = 0; c < 2; ++c) acc[r][c] = (float4_){0.f, 0.f, 0.f, 0.f};
    mma_step<8, KAUG, 0>(Q, Waug, acc, lane, cb);        // h part (k 0..255)
    __syncthreads();                                      // staging visible
    mma_step<5, KAUG, 256>(P, Waug, acc, lane, cb);      // state part (k 256..415)
    #pragma unroll
    for (int c = 0; c < 2; ++c) {
      int col = cb + c * 16 + rm;
      if (col < SDIM) {
        float bb = baug[col];
        #pragma unroll
        for (int r = 0; r < 4; ++r)
          #pragma unroll
          for (int i = 0; i < 4; ++i) {
            int row = r * 16 + rq * 4 + i;
            out[(size_t)(row0 + row) * SDIM + col] = acc[r][c][i] + bb;
          }
      }
    }
  }
}

extern "C" void kernel_launch(void* const* d_in, const int* in_sizes, int n_in,
                              void* d_out, int out_size, void* d_ws, size_t ws_size,
                              hipStream_t stream) {
  const float* t        = (const float*)d_in[0];
  const float* state    = (const float*)d_in[1];
  const float* W0       = (const float*)d_in[2];
  const float* b0       = (const float*)d_in[3];
  const float* blkW1    = (const float*)d_in[4];
  const float* blkb1    = (const float*)d_in[5];
  const float* blkW2    = (const float*)d_in[6];
  const float* blkb2    = (const float*)d_in[7];
  const float* Wout     = (const float*)d_in[8];
  const float* bout     = (const float*)d_in[9];
  const float* lm_in_w  = (const float*)d_in[10];
  const float* lm_in_b  = (const float*)d_in[11];
  const float* lm_out_w = (const float*)d_in[12];
  const float* lm_out_b = (const float*)d_in[13];
  const float* ta_in_w  = (const float*)d_in[14];
  const float* ta_in_b  = (const float*)d_in[15];
  const float* ta_out_w = (const float*)d_in[16];
  const float* ta_out_b = (const float*)d_in[17];

  char* ws = (char*)d_ws;
  unsigned short* W0p   = (unsigned short*)ws;                   // 256*160*2   = 81920
  float*          b0p   = (float*)(ws + 81920);                  // 1024
  unsigned short* Waug  = (unsigned short*)(ws + 82944);         // 256*416*2   = 212992
  float*          baug  = (float*)(ws + 295936);                 // 1024
  unsigned short* W1b   = (unsigned short*)(ws + 296960);        // 4*256*256*2 = 524288
  unsigned short* W2b   = (unsigned short*)(ws + 821248);        // 524288  (total ~1.31 MB)

  prep_w0<<<1, 256, 0, stream>>>(t, W0, b0, W0p, b0p);
  prep_waug<<<256, 64, 0, stream>>>(Wout, bout, lm_in_w, lm_in_b, lm_out_w, lm_out_b,
                                    ta_in_w, ta_in_b, ta_out_w, ta_out_b, Waug, baug);
  prep_blk<<<(262144 + 255) / 256, 256, 0, stream>>>(blkW1, W1b, 262144);
  prep_blk<<<(262144 + 255) / 256, 256, 0, stream>>>(blkW2, W2b, 262144);

  int batch = in_sizes[1] / SDIM;               // 131072
  fused_odefunc<<<batch / MTILE, NTHR, 0, stream>>>(
      state, W0p, b0p, W1b, blkb1, W2b, blkb2, Waug, baug,
      (float*)d_out);
}

// Round 4
// 575.398 us; speedup vs baseline: 1.4351x; 1.3245x over previous
//
#include <hip/hip_runtime.h>

typedef __attribute__((ext_vector_type(8))) short short8;
typedef __attribute__((ext_vector_type(4))) float float4_;

#define SDIM    137
#define HID     256
#define K0PAD   160     // state (137) padded to 5 k-blocks of 32
#define KAUG    416     // 256 (h) + 160 (state part)
#define MTILE   64
#define NTHR    512     // 8 waves; each wave owns a 32-out-col strip

struct __attribute__((aligned(8))) U2 { unsigned x, y; };

__device__ __forceinline__ unsigned short f2bf(float f) {
  union { float f; unsigned int i; } v; v.f = f;
  return (unsigned short)((v.i + 0x8000u) >> 16);   // round-half-up
}
// pack two floats -> two bf16 in one dword: low16 = bf16(a), high16 = bf16(b)
__device__ __forceinline__ unsigned pack_bf16(float a, float b) {
  union { float f; unsigned u; } ua, ub; ua.f = a; ub.f = b;
  return __builtin_amdgcn_perm(ub.u + 0x8000u, ua.u + 0x8000u, 0x07060302u);
}
__device__ __forceinline__ float lo_bf(unsigned p) {
  union { unsigned u; float f; } v; v.u = p << 16; return v.f;
}
__device__ __forceinline__ float hi_bf(unsigned p) {
  union { unsigned u; float f; } v; v.u = p & 0xFFFF0000u; return v.f;
}
// tanh(x) = 1 - 2/(e^{2x}+1); rcp handles +-inf -> saturates to +-1, no clamp needed.
__device__ __forceinline__ float fast_tanh(float x) {
  float e = __expf(2.f * x);
  float r = __builtin_amdgcn_rcpf(e + 1.f);
  return __builtin_fmaf(-2.f, r, 1.f);
}
// LDS index (in ushorts) for activation tiles: row stride 256 els, 16B-chunk XOR swizzle.
__device__ __forceinline__ int sidx(int row, int col) {
  return row * 256 + ((((col >> 3) ^ (row & 31)) << 3) | (col & 7));
}

// acc[2][4] += W(A-operand, global [M][K] row-major) @ X(B-operand, LDS swizzled)
// Wave owns out-col strip [colbase, colbase+32). Verified layouts (R2-passed kernel):
//   A: lane reads W row m = colbase+mt*16+(lane&15), k = kb*32+(lane>>4)*8 ..+7
//   B: lane reads X row n = nt*16+(lane&15), same k window (16B chunk kb*4+q)
// C/D: lane holds (out-col = colbase+mt*16+q*4+i, batch-row = nt*16+(lane&15))
template<int NK, int LDB, int BOFF>
__device__ __forceinline__ void mma_wact(const unsigned short* __restrict__ X,
                                         const unsigned short* __restrict__ W,
                                         float4_ (&acc)[2][4], int lane, int colbase)
{
  const int q  = lane >> 4;
  const int rm = lane & 15;
  #pragma unroll
  for (int kb = 0; kb < NK; ++kb) {
    short8 wa[2]; short8 xb[4];
    #pragma unroll
    for (int mt = 0; mt < 2; ++mt) {
      int m = colbase + mt * 16 + rm;
      wa[mt] = *(const short8*)(W + (size_t)m * LDB + BOFF + kb * 32 + q * 8);
    }
    #pragma unroll
    for (int nt = 0; nt < 4; ++nt) {
      int row = nt * 16 + rm;
      int c   = kb * 4 + q;
      xb[nt] = *(const short8*)(X + row * 256 + (((c ^ (row & 31)) << 3)));
    }
    #pragma unroll
    for (int mt = 0; mt < 2; ++mt)
      #pragma unroll
      for (int nt = 0; nt < 4; ++nt)
        acc[mt][nt] = __builtin_amdgcn_mfma_f32_16x16x32_bf16(wa[mt], xb[nt], acc[mt][nt], 0, 0, 0);
  }
}

// ---------------- prep kernels (tiny, once per launch) ----------------

__global__ void prep_w0(const float* __restrict__ t,
                        const float* __restrict__ W0,
                        const float* __restrict__ b0,
                        unsigned short* __restrict__ W0p,
                        float* __restrict__ b0p)
{
  int n = threadIdx.x;               // 256 threads
  float tv  = t[0];
  float ang = tv * (6.2831853071795864f / 24.0f);
  float sv = __sinf(ang), cv = __cosf(ang);
  for (int k = 0; k < K0PAD; ++k)
    W0p[n * K0PAD + k] = (k < SDIM) ? f2bf(W0[n * 139 + k]) : (unsigned short)0;
  b0p[n] = b0[n] + W0[n * 139 + 137] * sv + W0[n * 139 + 138] * cv;
}

// Waug[256][416] bf16: k<256 -> Wout (rows>=137 zero); k=256+s -> 0.1*(M - I) for the
// two collapsed seq-len-1 attentions (softmax over 1 key == 1 => MHA == out_w@Wv + consts).
// baug (fp32) folds bout + 0.1*(out_w@bv + out_b).
__global__ void prep_waug(const float* __restrict__ Wout,
                          const float* __restrict__ bout,
                          const float* __restrict__ lm_in_w,
                          const float* __restrict__ lm_in_b,
                          const float* __restrict__ lm_out_w,
                          const float* __restrict__ lm_out_b,
                          const float* __restrict__ ta_in_w,
                          const float* __restrict__ ta_in_b,
                          const float* __restrict__ ta_out_w,
                          const float* __restrict__ ta_out_b,
                          unsigned short* __restrict__ Waug,
                          float* __restrict__ baug)
{
  int n = blockIdx.x;                // 256 blocks
  int t = threadIdx.x;               // 64 threads
  for (int k = t; k < KAUG; k += 64) {
    float v = 0.f;
    if (k < 256) {
      if (n < SDIM) v = Wout[n * 256 + k];
    } else {
      int s = k - 256;
      if (s < 136) {
        if (n < 128 && s < 128) {
          float dot = 0.f;
          for (int r = 0; r < 128; ++r)
            dot += ta_out_w[n * 128 + r] * ta_in_w[(256 + r) * 128 + s];
          v = 0.1f * (dot - (s == n ? 1.f : 0.f));
        } else if (n >= 128 && n < 136 && s >= 128) {
          int a = n - 128, b = s - 128;
          float dot = 0.f;
          for (int r = 0; r < 8; ++r)
            dot += lm_out_w[a * 8 + r] * lm_in_w[(16 + r) * 8 + b];
          v = 0.1f * (dot - (s == n ? 1.f : 0.f));
        }
      }
    }
    Waug[n * KAUG + k] = f2bf(v);
  }
  if (t == 0) {
    float bb = 0.f;
    if (n < SDIM) bb = bout[n];
    if (n < 128) {
      float dot = 0.f;
      for (int r = 0; r < 128; ++r)
        dot += ta_out_w[n * 128 + r] * ta_in_b[256 + r];
      bb += 0.1f * (dot + ta_out_b[n]);
    } else if (n < 136) {
      int a = n - 128;
      float dot = 0.f;
      for (int r = 0; r < 8; ++r)
        dot += lm_out_w[a * 8 + r] * lm_in_b[16 + r];
      bb += 0.1f * (dot + lm_out_b[a]);
    }
    baug[n] = bb;
  }
}

__global__ void prep_blk(const float* __restrict__ src, unsigned short* __restrict__ dst, int n) {
  int i = blockIdx.x * 256 + threadIdx.x;
  if (i < n) dst[i] = f2bf(src[i]);
}

// ---------------- fused main kernel ----------------
// 512 thr / 8 waves; 64KB LDS arena -> 2 blocks/CU = 16 waves/CU; VGPR capped 128.

__global__ __launch_bounds__(NTHR)
__attribute__((amdgpu_waves_per_eu(4)))
void fused_odefunc(
    const float* __restrict__ state,
    const unsigned short* __restrict__ W0p,
    const float* __restrict__ b0p,
    const unsigned short* __restrict__ blkW1,
    const float* __restrict__ blkb1,
    const unsigned short* __restrict__ blkW2,
    const float* __restrict__ blkb2,
    const unsigned short* __restrict__ Waug,
    const float* __restrict__ baug,
    float* __restrict__ out)
{
  __shared__ __align__(16) unsigned short ARENA[2 * 64 * 256];   // 64 KiB
  unsigned short* H = ARENA;               // h tile (persists across blocks)
  unsigned short* G = ARENA + 64 * 256;    // state / g tile (ping)
  float*          T = (float*)ARENA;       // final fp32 out tile 64x140 (reuse)

  const int tid  = threadIdx.x;
  const int lane = tid & 63;
  const int wave = tid >> 6;               // 0..7
  const int q    = lane >> 4;
  const int rm   = lane & 15;
  const int cb   = wave * 32;              // this wave's out-col base
  const int row0 = blockIdx.x * MTILE;

  // ---- stage state tile (fp32 -> bf16, packed b64) -> G
  #pragma unroll 1
  for (int qd = tid; qd < 64 * (K0PAD / 4); qd += NTHR) {   // 2560 quads
    int m  = qd / (K0PAD / 4);
    int k0 = (qd - m * (K0PAD / 4)) * 4;
    const float* sp = state + (size_t)(row0 + m) * SDIM + k0;
    float f0 = (k0     < SDIM) ? sp[0] : 0.f;
    float f1 = (k0 + 1 < SDIM) ? sp[1] : 0.f;
    float f2 = (k0 + 2 < SDIM) ? sp[2] : 0.f;
    float f3 = (k0 + 3 < SDIM) ? sp[3] : 0.f;
    U2 p; p.x = pack_bf16(f0, f1); p.y = pack_bf16(f2, f3);
    *(U2*)(&G[sidx(m, k0)]) = p;
  }
  __syncthreads();

  // ---- layer 0: h = relu(W0p @ state^T) -> H
  {
    float4_ acc[2][4];
    #pragma unroll
    for (int mt = 0; mt < 2; ++mt)
      #pragma unroll
      for (int nt = 0; nt < 4; ++nt) acc[mt][nt] = (float4_){0.f, 0.f, 0.f, 0.f};
    mma_wact<K0PAD / 32, K0PAD, 0>(G, W0p, acc, lane, cb);
    #pragma unroll
    for (int mt = 0; mt < 2; ++mt) {
      int col0 = cb + mt * 16 + q * 4;
      float4_ bias = *(const float4_*)(b0p + col0);
      #pragma unroll
      for (int nt = 0; nt < 4; ++nt) {
        int row = nt * 16 + rm;
        float v0 = fmaxf(acc[mt][nt][0] + bias[0], 0.f);
        float v1 = fmaxf(acc[mt][nt][1] + bias[1], 0.f);
        float v2 = fmaxf(acc[mt][nt][2] + bias[2], 0.f);
        float v3 = fmaxf(acc[mt][nt][3] + bias[3], 0.f);
        U2 p; p.x = pack_bf16(v0, v1); p.y = pack_bf16(v2, v3);
        *(U2*)(&H[sidx(row, col0)]) = p;
      }
    }
  }
  __syncthreads();

  // ---- 4 residual blocks: g = tanh(W1@h^T+b1) -> G;  h = tanh(h + W2@g^T+b2) in-place in H
  for (int blk = 0; blk < 4; ++blk) {
    const unsigned short* W1 = blkW1 + (size_t)blk * 65536;
    const float*          b1 = blkb1 + blk * 256;
    const unsigned short* W2 = blkW2 + (size_t)blk * 65536;
    const float*          b2 = blkb2 + blk * 256;

    float4_ acc[2][4];
    #pragma unroll
    for (int mt = 0; mt < 2; ++mt)
      #pragma unroll
      for (int nt = 0; nt < 4; ++nt) acc[mt][nt] = (float4_){0.f, 0.f, 0.f, 0.f};
    mma_wact<8, 256, 0>(H, W1, acc, lane, cb);
    #pragma unroll
    for (int mt = 0; mt < 2; ++mt) {
      int col0 = cb + mt * 16 + q * 4;
      float4_ bias = *(const float4_*)(b1 + col0);
      #pragma unroll
      for (int nt = 0; nt < 4; ++nt) {
        int row = nt * 16 + rm;
        float v0 = fast_tanh(acc[mt][nt][0] + bias[0]);
        float v1 = fast_tanh(acc[mt][nt][1] + bias[1]);
        float v2 = fast_tanh(acc[mt][nt][2] + bias[2]);
        float v3 = fast_tanh(acc[mt][nt][3] + bias[3]);
        U2 p; p.x = pack_bf16(v0, v1); p.y = pack_bf16(v2, v3);
        *(U2*)(&G[sidx(row, col0)]) = p;
      }
    }
    __syncthreads();

    #pragma unroll
    for (int mt = 0; mt < 2; ++mt)
      #pragma unroll
      for (int nt = 0; nt < 4; ++nt) acc[mt][nt] = (float4_){0.f, 0.f, 0.f, 0.f};
    mma_wact<8, 256, 0>(G, W2, acc, lane, cb);
    #pragma unroll
    for (int mt = 0; mt < 2; ++mt) {
      int col0 = cb + mt * 16 + q * 4;
      float4_ bias = *(const float4_*)(b2 + col0);
      #pragma unroll
      for (int nt = 0; nt < 4; ++nt) {
        int row = nt * 16 + rm;
        int idx = sidx(row, col0);
        U2 old = *(const U2*)(&H[idx]);                 // lane-owned slots
        float v0 = fast_tanh(lo_bf(old.x) + acc[mt][nt][0] + bias[0]);
        float v1 = fast_tanh(hi_bf(old.x) + acc[mt][nt][1] + bias[1]);
        float v2 = fast_tanh(lo_bf(old.y) + acc[mt][nt][2] + bias[2]);
        float v3 = fast_tanh(hi_bf(old.y) + acc[mt][nt][3] + bias[3]);
        U2 p; p.x = pack_bf16(v0, v1); p.y = pack_bf16(v2, v3);
        *(U2*)(&H[idx]) = p;
      }
    }
    __syncthreads();
  }

  // ---- final: out = Waug @ [h; state]^T + baug  (only out-cols < 160 needed)
  // restage state -> G (G dead since last GEMM2; safe before barrier, H-readers unaffected)
  #pragma unroll 1
  for (int qd = tid; qd < 64 * (K0PAD / 4); qd += NTHR) {
    int m  = qd / (K0PAD / 4);
    int k0 = (qd - m * (K0PAD / 4)) * 4;
    const float* sp = state + (size_t)(row0 + m) * SDIM + k0;
    float f0 = (k0     < SDIM) ? sp[0] : 0.f;
    float f1 = (k0 + 1 < SDIM) ? sp[1] : 0.f;
    float f2 = (k0 + 2 < SDIM) ? sp[2] : 0.f;
    float f3 = (k0 + 3 < SDIM) ? sp[3] : 0.f;
    U2 p; p.x = pack_bf16(f0, f1); p.y = pack_bf16(f2, f3);
    *(U2*)(&G[sidx(m, k0)]) = p;
  }

  float4_ acc[2][4];
  #pragma unroll
  for (int mt = 0; mt < 2; ++mt)
    #pragma unroll
    for (int nt = 0; nt < 4; ++nt) acc[mt][nt] = (float4_){0.f, 0.f, 0.f, 0.f};
  if (cb < 160)
    mma_wact<8, KAUG, 0>(H, Waug, acc, lane, cb);        // h part (k 0..255)
  __syncthreads();                                       // G staged + H reads done
  if (cb < 160)
    mma_wact<5, KAUG, 256>(G, Waug, acc, lane, cb);      // state part (k 256..415)
  __syncthreads();                                       // all arena reads done
  if (cb < 160) {
    #pragma unroll
    for (int mt = 0; mt < 2; ++mt) {
      int col0 = cb + mt * 16 + q * 4;
      if (col0 <= 136) {
        float4_ bias = *(const float4_*)(baug + col0);
        #pragma unroll
        for (int nt = 0; nt < 4; ++nt) {
          int row = nt * 16 + rm;
          float4_ v;
          v[0] = acc[mt][nt][0] + bias[0];
          v[1] = acc[mt][nt][1] + bias[1];
          v[2] = acc[mt][nt][2] + bias[2];
          v[3] = acc[mt][nt][3] + bias[3];
          *(float4_*)(T + row * 140 + col0) = v;        // fp32 tile, stride 140
        }
      }
    }
  }
  __syncthreads();

  // ---- fully coalesced linear store: 64*137 contiguous floats
  float* obase = out + (size_t)row0 * SDIM;
  #pragma unroll 1
  for (int idx = tid; idx < MTILE * SDIM; idx += NTHR) {
    int r = idx / SDIM;
    int c = idx - r * SDIM;
    obase[idx] = T[r * 140 + c];
  }
}

extern "C" void kernel_launch(void* const* d_in, const int* in_sizes, int n_in,
                              void* d_out, int out_size, void* d_ws, size_t ws_size,
                              hipStream_t stream) {
  const float* t        = (const float*)d_in[0];
  const float* state    = (const float*)d_in[1];
  const float* W0       = (const float*)d_in[2];
  const float* b0       = (const float*)d_in[3];
  const float* blkW1    = (const float*)d_in[4];
  const float* blkb1    = (const float*)d_in[5];
  const float* blkW2    = (const float*)d_in[6];
  const float* blkb2    = (const float*)d_in[7];
  const float* Wout     = (const float*)d_in[8];
  const float* bout     = (const float*)d_in[9];
  const float* lm_in_w  = (const float*)d_in[10];
  const float* lm_in_b  = (const float*)d_in[11];
  const float* lm_out_w = (const float*)d_in[12];
  const float* lm_out_b = (const float*)d_in[13];
  const float* ta_in_w  = (const float*)d_in[14];
  const float* ta_in_b  = (const float*)d_in[15];
  const float* ta_out_w = (const float*)d_in[16];
  const float* ta_out_b = (const float*)d_in[17];

  char* ws = (char*)d_ws;
  unsigned short* W0p   = (unsigned short*)ws;                   // 256*160*2   = 81920
  float*          b0p   = (float*)(ws + 81920);                  // 1024
  unsigned short* Waug  = (unsigned short*)(ws + 82944);         // 256*416*2   = 212992
  float*          baug  = (float*)(ws + 295936);                 // 1024
  unsigned short* W1b   = (unsigned short*)(ws + 296960);        // 4*256*256*2 = 524288
  unsigned short* W2b   = (unsigned short*)(ws + 821248);        // 524288  (total ~1.31 MB)

  prep_w0<<<1, 256, 0, stream>>>(t, W0, b0, W0p, b0p);
  prep_waug<<<256, 64, 0, stream>>>(Wout, bout, lm_in_w, lm_in_b, lm_out_w, lm_out_b,
                                    ta_in_w, ta_in_b, ta_out_w, ta_out_b, Waug, baug);
  prep_blk<<<(262144 + 255) / 256, 256, 0, stream>>>(blkW1, W1b, 262144);
  prep_blk<<<(262144 + 255) / 256, 256, 0, stream>>>(blkW2, W2b, 262144);

  int batch = in_sizes[1] / SDIM;               // 131072
  fused_odefunc<<<batch / MTILE, NTHR, 0, stream>>>(
      state, W0p, b0p, W1b, blkb1, W2b, blkb2, Waug, baug,
      (float*)d_out);
}